// Round 10
// baseline (106.032 us; speedup 1.0000x reference)
//
#include <hip/hip_runtime.h>
#include <hip/hip_bf16.h>

#define BB 128
#define SS 512
#define NPOS (BB*SS)          // 65536
#define DD 256
#define KIND_D 8
#define EXPR_D 512
#define KOS_VOCAB 256
#define NUM_IDS 8192
#define IDENTIFIER_KIND 3
#define TROWS 9088            // padded table rows (8968 used) = 71*128

typedef unsigned short u16;
typedef __attribute__((ext_vector_type(8))) short s16x8;           // 8 bf16 (4 VGPRs)
typedef __attribute__((ext_vector_type(8))) unsigned short u16x8;  // 16B unit
typedef __attribute__((ext_vector_type(4))) float f32x4;

__device__ __forceinline__ u16 bf16bits(float v) {
    __hip_bfloat16 h = __float2bfloat16(v);
    return *(u16*)&h;
}
__device__ __forceinline__ float bf16tof(u16 b) {
    __hip_bfloat16 h = *(__hip_bfloat16*)&b;
    return __bfloat162float(h);
}

// ---------------- Kernel 1: prep ----------------
// blocks 0..255   : W2 [512k][512n] f32 -> Wt [n][k] bf16
// block  256      : kindc[kind][j] = kind_emb[kind] @ W_proj[0:8] + b_proj
// blocks 257..384 : W_proj[8:264] [256k][512n] f32 -> Wt1 [n][k] bf16
// blocks 385..640 : per-256-chunk {id,kos} counts of token_type -> blkcnt
__global__ __launch_bounds__(256) void prep_kernel(const float* __restrict__ W2,
                                                   const float* __restrict__ kind_emb,
                                                   const float* __restrict__ Wp,
                                                   const float* __restrict__ bp,
                                                   const int* __restrict__ token_type,
                                                   u16* __restrict__ Wt,
                                                   u16* __restrict__ Wt1,
                                                   float* __restrict__ kindc,
                                                   int2* __restrict__ blkcnt) {
    __shared__ float tile[32][33];
    __shared__ int swid[4], swkos[4];
    const int bi = blockIdx.x;
    const int t = threadIdx.x;

    if (bi < 256) {
        const int n0 = (bi & 15) * 32;
        const int k0 = (bi >> 4) * 32;
        const int lj = t & 31, li = t >> 5;
        #pragma unroll
        for (int p = 0; p < 4; ++p) {
            int i = li + p * 8;
            tile[i][lj] = W2[(size_t)(k0 + i) * EXPR_D + n0 + lj];
        }
        __syncthreads();
        #pragma unroll
        for (int p = 0; p < 4; ++p) {
            int j = li + p * 8;
            Wt[(size_t)(n0 + j) * EXPR_D + k0 + lj] = bf16bits(tile[lj][j]);
        }
    } else if (bi == 256) {
        #pragma unroll
        for (int rep = 0; rep < 2; ++rep) {
            int j = t + rep * 256;
            float bias = bp[j];
            for (int kind = 0; kind < 8; ++kind) {
                float a = bias;
                #pragma unroll
                for (int d = 0; d < KIND_D; ++d)
                    a = fmaf(kind_emb[kind * KIND_D + d], Wp[d * EXPR_D + j], a);
                kindc[kind * EXPR_D + j] = a;
            }
        }
    } else if (bi < 385) {
        const int idx = bi - 257;
        const int n0 = (idx & 15) * 32;
        const int k0 = (idx >> 4) * 32;
        const float* W1p = Wp + (size_t)KIND_D * EXPR_D;
        const int lj = t & 31, li = t >> 5;
        #pragma unroll
        for (int p = 0; p < 4; ++p) {
            int i = li + p * 8;
            tile[i][lj] = W1p[(size_t)(k0 + i) * EXPR_D + n0 + lj];
        }
        __syncthreads();
        #pragma unroll
        for (int p = 0; p < 4; ++p) {
            int j = li + p * 8;
            Wt1[(size_t)(n0 + j) * DD + k0 + lj] = bf16bits(tile[lj][j]);
        }
    } else {
        const int blk = bi - 385;
        const int lane = t & 63, wave = t >> 6;
        int k = token_type[blk * 256 + t];
        unsigned long long mid  = __ballot(k == IDENTIFIER_KIND);
        unsigned long long mkos = __ballot(k >= 4 && k <= 6);
        if (lane == 0) { swid[wave] = __popcll(mid); swkos[wave] = __popcll(mkos); }
        __syncthreads();
        if (t == 0) {
            int a = 0, c = 0;
            #pragma unroll
            for (int w = 0; w < 4; ++w) { a += swid[w]; c += swkos[w]; }
            blkcnt[blk] = make_int2(a, c);
        }
    }
}

// ---------------- Kernel 2: scatter -> sel2[] (direct table-row index) ----------------
// id rows: 0..8191 ; kos rows: 8192 + (kind-4)*256 + kos_idx ; none: 8960 + kind
__global__ __launch_bounds__(256) void scatter_kernel(const int* __restrict__ token_type,
                                                      const int2* __restrict__ blkcnt,
                                                      const int* __restrict__ kos_idx,
                                                      const int* __restrict__ id_idx,
                                                      int* __restrict__ sel2) {
    __shared__ int2 sbase;
    __shared__ int swid[4], swkos[4];
    const int b = blockIdx.x, t = threadIdx.x;
    const int lane = t & 63, wave = t >> 6;
    if (t < 64) {
        int a = 0, c = 0;
        for (int i = t; i < b; i += 64) { int2 v = blkcnt[i]; a += v.x; c += v.y; }
        #pragma unroll
        for (int off = 32; off; off >>= 1) { a += __shfl_down(a, off); c += __shfl_down(c, off); }
        if (t == 0) sbase = make_int2(a, c);
    }
    const int idx = b * 256 + t;
    const int k = token_type[idx];
    const bool fid  = (k == IDENTIFIER_KIND);
    const bool fkos = (k >= 4 && k <= 6);
    unsigned long long mid  = __ballot(fid);
    unsigned long long mkos = __ballot(fkos);
    if (lane == 0) { swid[wave] = __popcll(mid); swkos[wave] = __popcll(mkos); }
    __syncthreads();
    int bid = 0, bkos = 0;
    for (int w = 0; w < wave; ++w) { bid += swid[w]; bkos += swkos[w]; }
    unsigned long long below = (1ull << lane) - 1ull;
    int s;
    if (fid)       s = id_idx[sbase.x + bid + __popcll(mid & below)];
    else if (fkos) s = 8192 + (k - 4) * 256 + kos_idx[sbase.y + bkos + __popcll(mkos & below)];
    else           s = 8960 + k;
    sel2[idx] = s;
}

// ---------------- Kernel 3: build Thi = bf16(relu(kindc[kind] + x @ W1)) ----------------
// rows: 0..8191 = enc_ids (kind 3); 8192..8959 = kos (kind 4+q>>8); 8960..8967 = zero src.
__global__ __launch_bounds__(512, 2) void table_kernel(const float* __restrict__ enc_ids,
                                                       const float* __restrict__ kos_emb,
                                                       const u16* __restrict__ Wt1,
                                                       const float* __restrict__ kindc,
                                                       u16* __restrict__ Thi) {
    __shared__ u16 sAhi[2][128 * 64];
    __shared__ u16 sAlo[2][128 * 64];
    __shared__ u16 sB[2][256 * 64];

    const int t = threadIdx.x;
    const int row0 = blockIdx.x * 128;
    const int col0 = blockIdx.y * 256;

    const int ar = t >> 2;
    const int ac = (t & 3) * 16;
    const int br = t >> 1;
    const int bc = (t & 1) * 32;

    const int arow = row0 + ar;
    const float* Arow;
    bool hasrc = true;
    if (arow < NUM_IDS)        Arow = &enc_ids[(size_t)arow * DD];
    else if (arow < 8960)      Arow = &kos_emb[(size_t)((arow - NUM_IDS) & 255) * DD];
    else { Arow = enc_ids; hasrc = false; }
    const u16* Brow = &Wt1[(size_t)(col0 + br) * DD];

    const int lane = t & 63;
    const int wid  = t >> 6;
    const int wr = wid >> 2, wc = wid & 3;
    const int lrow = lane & 15, lkg = lane >> 4;

    f32x4 acc[4][4];
    #pragma unroll
    for (int mi = 0; mi < 4; ++mi)
        #pragma unroll
        for (int ni = 0; ni < 4; ++ni)
            acc[mi][ni] = (f32x4){0.f, 0.f, 0.f, 0.f};

    f32x4 av[4];
    u16x8 bv[4];

    auto STAGE_ISSUE = [&](int kc) {
        const int kb = kc * 64;
        #pragma unroll
        for (int j = 0; j < 4; ++j)
            av[j] = hasrc ? *(const f32x4*)&Arow[kb + ac + j * 4] : (f32x4){0.f,0.f,0.f,0.f};
        #pragma unroll
        for (int j = 0; j < 4; ++j) bv[j] = *(const u16x8*)&Brow[kb + bc + j * 8];
    };

    auto WRITE = [&](int buf) {
        u16 hi[16], lo[16];
        #pragma unroll
        for (int j = 0; j < 4; ++j)
            #pragma unroll
            for (int e = 0; e < 4; ++e) {
                float r = av[j][e];
                u16 h = bf16bits(r);
                hi[j * 4 + e] = h;
                lo[j * 4 + e] = bf16bits(r - bf16tof(h));
            }
        const int abase = ar * 128;
        const int o0 = abase + ((ac * 2) ^ ((ar & 7) << 4));
        const int o1 = abase + ((ac * 2 + 16) ^ ((ar & 7) << 4));
        *(u16x8*)((char*)sAhi[buf] + o0) = *(const u16x8*)&hi[0];
        *(u16x8*)((char*)sAhi[buf] + o1) = *(const u16x8*)&hi[8];
        *(u16x8*)((char*)sAlo[buf] + o0) = *(const u16x8*)&lo[0];
        *(u16x8*)((char*)sAlo[buf] + o1) = *(const u16x8*)&lo[8];
        const int bbase = br * 128;
        #pragma unroll
        for (int j = 0; j < 4; ++j) {
            int off = bbase + ((bc * 2 + j * 16) ^ ((br & 7) << 4));
            *(u16x8*)((char*)sB[buf] + off) = bv[j];
        }
    };

    auto COMPUTE = [&](int buf) {
        #pragma unroll
        for (int ks = 0; ks < 2; ++ks) {
            s16x8 ah[4], al[4], bbf[4];
            #pragma unroll
            for (int mi = 0; mi < 4; ++mi) {
                int row = wr * 64 + mi * 16 + lrow;
                int off = row * 128 + ((ks * 64 + lkg * 16) ^ ((row & 7) << 4));
                ah[mi] = *(const s16x8*)((const char*)sAhi[buf] + off);
                al[mi] = *(const s16x8*)((const char*)sAlo[buf] + off);
            }
            #pragma unroll
            for (int ni = 0; ni < 4; ++ni) {
                int row = wc * 64 + ni * 16 + lrow;
                int off = row * 128 + ((ks * 64 + lkg * 16) ^ ((row & 7) << 4));
                bbf[ni] = *(const s16x8*)((const char*)sB[buf] + off);
            }
            #pragma unroll
            for (int mi = 0; mi < 4; ++mi)
                #pragma unroll
                for (int ni = 0; ni < 4; ++ni) {
                    acc[mi][ni] = __builtin_amdgcn_mfma_f32_16x16x32_bf16(ah[mi], bbf[ni], acc[mi][ni], 0, 0, 0);
                    acc[mi][ni] = __builtin_amdgcn_mfma_f32_16x16x32_bf16(al[mi], bbf[ni], acc[mi][ni], 0, 0, 0);
                }
        }
    };

    STAGE_ISSUE(0);
    WRITE(0);
    __syncthreads();
    int cur = 0;
    #pragma unroll 1
    for (int kc = 0; kc < 4; ++kc) {
        if (kc < 3) STAGE_ISSUE(kc + 1);
        COMPUTE(cur);
        if (kc < 3) WRITE(cur ^ 1);
        __syncthreads();
        cur ^= 1;
    }

    // epilogue: add kindc[kind(row)], relu, bf16, store
    #pragma unroll
    for (int ni = 0; ni < 4; ++ni) {
        int col = col0 + wc * 64 + ni * 16 + lrow;
        #pragma unroll
        for (int mi = 0; mi < 4; ++mi) {
            int rbase = row0 + wr * 64 + mi * 16 + lkg * 4;
            #pragma unroll
            for (int j = 0; j < 4; ++j) {
                int rg = rbase + j;
                int kind = (rg < NUM_IDS) ? 3
                         : (rg < 8960) ? 4 + ((rg - NUM_IDS) >> 8)
                         : (rg < 8968) ? (rg - 8960) : 0;
                float v = acc[mi][ni][j] + kindc[kind * EXPR_D + col];
                Thi[(size_t)rg * EXPR_D + col] = bf16bits(fmaxf(v, 0.f));
            }
        }
    }
}

// ---------------- Kernel 4: Obf = bf16(relu(Thi @ Wt^T + b2))  (table-level layer 2) ----
// BM=128, BN=256, BK=32 (16 chunks), 512 threads (2x4 waves), dbuf LDS = 48 KiB.
// Identical to the proven round-8 kernel except the epilogue stores bf16.
__global__ __launch_bounds__(512, 4) void table2_kernel(const u16* __restrict__ Thi,
                                                        const u16* __restrict__ Wt,
                                                        const float* __restrict__ b2,
                                                        u16* __restrict__ Obf) {
    __shared__ u16 sA[2][128 * 32];
    __shared__ u16 sB[2][256 * 32];

    const int t = threadIdx.x;
    const int row0 = blockIdx.x * 128;
    const int col0 = blockIdx.y * 256;

    const int ar = t >> 2;
    const int ac8 = (t & 3) * 8;
    const int br = t >> 1;
    const int bc16 = (t & 1) * 16;

    const u16* Arow = &Thi[(size_t)(row0 + ar) * EXPR_D + ac8];
    const u16* Brow = &Wt[(size_t)(col0 + br) * EXPR_D + bc16];

    const int lane = t & 63;
    const int wid  = t >> 6;
    const int wr = wid >> 2, wc = wid & 3;
    const int lrow = lane & 15, lkg = lane >> 4;

    f32x4 acc[4][4];
    #pragma unroll
    for (int mi = 0; mi < 4; ++mi)
        #pragma unroll
        for (int ni = 0; ni < 4; ++ni)
            acc[mi][ni] = (f32x4){0.f, 0.f, 0.f, 0.f};

    u16x8 av;
    u16x8 bv[2];

    auto STAGE_ISSUE = [&](int kc) {
        const int kb = kc * 32;
        av = *(const u16x8*)&Arow[kb];
        bv[0] = *(const u16x8*)&Brow[kb];
        bv[1] = *(const u16x8*)&Brow[kb + 8];
    };

    auto WRITE = [&](int buf) {
        int aoff = ar * 64 + ((ac8 * 2) ^ ((ar & 3) << 4));
        *(u16x8*)((char*)sA[buf] + aoff) = av;
        #pragma unroll
        for (int j = 0; j < 2; ++j) {
            int boff = br * 64 + ((bc16 * 2 + j * 16) ^ ((br & 3) << 4));
            *(u16x8*)((char*)sB[buf] + boff) = bv[j];
        }
    };

    auto COMPUTE = [&](int buf) {
        s16x8 a[4], b[4];
        #pragma unroll
        for (int mi = 0; mi < 4; ++mi) {
            int row = wr * 64 + mi * 16 + lrow;
            int off = row * 64 + ((lkg * 16) ^ ((row & 3) << 4));
            a[mi] = *(const s16x8*)((const char*)sA[buf] + off);
        }
        #pragma unroll
        for (int ni = 0; ni < 4; ++ni) {
            int row = wc * 64 + ni * 16 + lrow;
            int off = row * 64 + ((lkg * 16) ^ ((row & 3) << 4));
            b[ni] = *(const s16x8*)((const char*)sB[buf] + off);
        }
        #pragma unroll
        for (int mi = 0; mi < 4; ++mi)
            #pragma unroll
            for (int ni = 0; ni < 4; ++ni)
                acc[mi][ni] = __builtin_amdgcn_mfma_f32_16x16x32_bf16(a[mi], b[ni], acc[mi][ni], 0, 0, 0);
    };

    STAGE_ISSUE(0);
    WRITE(0);
    __syncthreads();
    int cur = 0;
    #pragma unroll 1
    for (int kc = 0; kc < 16; ++kc) {
        if (kc < 15) STAGE_ISSUE(kc + 1);
        COMPUTE(cur);
        if (kc < 15) WRITE(cur ^ 1);
        __syncthreads();
        cur ^= 1;
    }

    #pragma unroll
    for (int ni = 0; ni < 4; ++ni) {
        int col = col0 + wc * 64 + ni * 16 + lrow;
        float bias = b2[col];
        #pragma unroll
        for (int mi = 0; mi < 4; ++mi) {
            int rbase = row0 + wr * 64 + mi * 16 + lkg * 4;
            #pragma unroll
            for (int j = 0; j < 4; ++j)
                Obf[(size_t)(rbase + j) * EXPR_D + col] = bf16bits(fmaxf(acc[mi][ni][j] + bias, 0.f));
        }
    }
}

// ---------------- Kernel 5: out[pos] = f32(Obf[sel2[pos]])  (gather + upconvert) ----------
// 4 waves/block, 16 positions/block; load all 4 rows (16B/lane) first, then store f32.
__global__ __launch_bounds__(256) void gather_kernel(const int* __restrict__ sel2,
                                                     const u16* __restrict__ Obf,
                                                     float* __restrict__ out) {
    const int t = threadIdx.x;
    const int lane = t & 63, wave = t >> 6;
    const int base = blockIdx.x * 16;
    int rows[4];
    #pragma unroll
    for (int i = 0; i < 4; ++i) rows[i] = sel2[base + i * 4 + wave];
    u16x8 r[4];
    #pragma unroll
    for (int i = 0; i < 4; ++i)
        r[i] = *(const u16x8*)&Obf[(size_t)rows[i] * EXPR_D + lane * 8];
    #pragma unroll
    for (int i = 0; i < 4; ++i) {
        const int pos = base + i * 4 + wave;
        float* dst = &out[(size_t)pos * EXPR_D + lane * 8];
        f32x4 lo, hi;
        #pragma unroll
        for (int e = 0; e < 4; ++e) {
            lo[e] = bf16tof((u16)r[i][e]);
            hi[e] = bf16tof((u16)r[i][e + 4]);
        }
        __builtin_nontemporal_store(lo, (f32x4*)dst);
        __builtin_nontemporal_store(hi, (f32x4*)(dst + 4));
    }
}

extern "C" void kernel_launch(void* const* d_in, const int* in_sizes, int n_in,
                              void* d_out, int out_size, void* d_ws, size_t ws_size,
                              hipStream_t stream) {
    const int*   token_type = (const int*)d_in[0];
    const int*   kos_idx    = (const int*)d_in[1];
    const int*   id_idx     = (const int*)d_in[2];
    const float* enc_ids    = (const float*)d_in[3];
    const float* kind_emb   = (const float*)d_in[4];
    const float* kos_emb    = (const float*)d_in[5];
    const float* Wp         = (const float*)d_in[6];
    const float* bp         = (const float*)d_in[7];
    const float* W2         = (const float*)d_in[8];
    const float* b2         = (const float*)d_in[9];
    float* out = (float*)d_out;

    char* ws = (char*)d_ws;
    int*   sel2   = (int*)ws;                          // 256 KiB
    float* kindc  = (float*)(ws + 262144);             // 16 KiB
    int2*  blkcnt = (int2*)(ws + 278528);              // 4 KiB
    u16*   Wt     = (u16*)(ws + 282624);               // 512 KiB
    u16*   Wt1    = (u16*)(ws + 806912);               // 256 KiB
    u16*   Thi    = (u16*)(ws + 1069056);              // TROWS*512*2 = 9306112
    u16*   Obf    = (u16*)(ws + 10375168);             // TROWS*512*2 = 9306112 (~19.7 MB)

    hipLaunchKernelGGL(prep_kernel, dim3(641), dim3(256), 0, stream,
                       W2, kind_emb, Wp, bp, token_type, Wt, Wt1, kindc, blkcnt);
    hipLaunchKernelGGL(scatter_kernel, dim3(256), dim3(256), 0, stream,
                       token_type, blkcnt, kos_idx, id_idx, sel2);
    hipLaunchKernelGGL(table_kernel, dim3(TROWS / 128, EXPR_D / 256), dim3(512), 0, stream,
                       enc_ids, kos_emb, Wt1, kindc, Thi);
    hipLaunchKernelGGL(table2_kernel, dim3(TROWS / 128, EXPR_D / 256), dim3(512), 0, stream,
                       Thi, Wt, b2, Obf);
    hipLaunchKernelGGL(gather_kernel, dim3(NPOS / 16), dim3(256), 0, stream,
                       sel2, Obf, out);
}

// Round 11
// 81.364 us; speedup vs baseline: 1.3032x; 1.3032x over previous
//
#include <hip/hip_runtime.h>
#include <hip/hip_bf16.h>

#define BB 128
#define SS 512
#define NPOS (BB*SS)          // 65536
#define DD 256
#define KIND_D 8
#define EXPR_D 512
#define KOS_VOCAB 256
#define NUM_IDS 8192
#define IDENTIFIER_KIND 3
#define TROWS 9088            // padded table rows (8968 used) = 71*128

typedef unsigned short u16;
typedef __attribute__((ext_vector_type(8))) short s16x8;           // 8 bf16 (4 VGPRs)
typedef __attribute__((ext_vector_type(8))) unsigned short u16x8;  // 16B unit
typedef __attribute__((ext_vector_type(4))) float f32x4;

__device__ __forceinline__ u16 bf16bits(float v) {
    __hip_bfloat16 h = __float2bfloat16(v);
    return *(u16*)&h;
}
__device__ __forceinline__ float bf16tof(u16 b) {
    __hip_bfloat16 h = *(__hip_bfloat16*)&b;
    return __bfloat162float(h);
}

// ---------------- Kernel 1: prep ----------------
// blocks 0..255   : W2 [512k][512n] f32 -> Wt [n][k] bf16
// block  256      : kindc[kind][j] = kind_emb[kind] @ W_proj[0:8] + b_proj
// blocks 257..384 : W_proj[8:264] [256k][512n] f32 -> Wt1 [n][k] bf16
// blocks 385..640 : self-counting scatter: chunk q = bi-385 -> sel2[q*256 .. +256)
__global__ __launch_bounds__(256) void prep_kernel(const float* __restrict__ W2,
                                                   const float* __restrict__ kind_emb,
                                                   const float* __restrict__ Wp,
                                                   const float* __restrict__ bp,
                                                   const int* __restrict__ token_type,
                                                   const int* __restrict__ kos_idx,
                                                   const int* __restrict__ id_idx,
                                                   u16* __restrict__ Wt,
                                                   u16* __restrict__ Wt1,
                                                   float* __restrict__ kindc,
                                                   int* __restrict__ sel2) {
    __shared__ float tile[32][33];
    __shared__ int swid[4], swkos[4];
    const int bi = blockIdx.x;
    const int t = threadIdx.x;

    if (bi < 256) {
        const int n0 = (bi & 15) * 32;
        const int k0 = (bi >> 4) * 32;
        const int lj = t & 31, li = t >> 5;
        #pragma unroll
        for (int p = 0; p < 4; ++p) {
            int i = li + p * 8;
            tile[i][lj] = W2[(size_t)(k0 + i) * EXPR_D + n0 + lj];
        }
        __syncthreads();
        #pragma unroll
        for (int p = 0; p < 4; ++p) {
            int j = li + p * 8;
            Wt[(size_t)(n0 + j) * EXPR_D + k0 + lj] = bf16bits(tile[lj][j]);
        }
    } else if (bi == 256) {
        #pragma unroll
        for (int rep = 0; rep < 2; ++rep) {
            int j = t + rep * 256;
            float bias = bp[j];
            for (int kind = 0; kind < 8; ++kind) {
                float a = bias;
                #pragma unroll
                for (int d = 0; d < KIND_D; ++d)
                    a = fmaf(kind_emb[kind * KIND_D + d], Wp[d * EXPR_D + j], a);
                kindc[kind * EXPR_D + j] = a;
            }
        }
    } else if (bi < 385) {
        const int idx = bi - 257;
        const int n0 = (idx & 15) * 32;
        const int k0 = (idx >> 4) * 32;
        const float* W1p = Wp + (size_t)KIND_D * EXPR_D;
        const int lj = t & 31, li = t >> 5;
        #pragma unroll
        for (int p = 0; p < 4; ++p) {
            int i = li + p * 8;
            tile[i][lj] = W1p[(size_t)(k0 + i) * EXPR_D + n0 + lj];
        }
        __syncthreads();
        #pragma unroll
        for (int p = 0; p < 4; ++p) {
            int j = li + p * 8;
            Wt1[(size_t)(n0 + j) * DD + k0 + lj] = bf16bits(tile[lj][j]);
        }
    } else {
        // ---- self-counting scatter for position chunk q ----
        const int q = bi - 385;                 // 0..255
        const int lane = t & 63, wave = t >> 6;
        // exclusive prefix: count id/kos in positions [0, q*256), int4-vectorized
        int a = 0, c = 0;
        const int total = q * 256;
        for (int i = t * 4; i + 3 < total; i += 1024) {
            int4 kk = *(const int4*)&token_type[i];
            a += (kk.x == 3) + (kk.y == 3) + (kk.z == 3) + (kk.w == 3);
            c += (kk.x >= 4 && kk.x <= 6) + (kk.y >= 4 && kk.y <= 6)
               + (kk.z >= 4 && kk.z <= 6) + (kk.w >= 4 && kk.w <= 6);
        }
        #pragma unroll
        for (int off = 32; off; off >>= 1) { a += __shfl_down(a, off); c += __shfl_down(c, off); }
        if (lane == 0) { swid[wave] = a; swkos[wave] = c; }
        __syncthreads();
        const int base_id  = swid[0] + swid[1] + swid[2] + swid[3];
        const int base_kos = swkos[0] + swkos[1] + swkos[2] + swkos[3];
        __syncthreads();   // before reusing swid/swkos
        // in-chunk ballot rank (identical to prior scatter kernel)
        const int idx = q * 256 + t;
        const int k = token_type[idx];
        const bool fid  = (k == IDENTIFIER_KIND);
        const bool fkos = (k >= 4 && k <= 6);
        unsigned long long mid  = __ballot(fid);
        unsigned long long mkos = __ballot(fkos);
        if (lane == 0) { swid[wave] = __popcll(mid); swkos[wave] = __popcll(mkos); }
        __syncthreads();
        int bid = 0, bkos = 0;
        for (int w = 0; w < wave; ++w) { bid += swid[w]; bkos += swkos[w]; }
        unsigned long long below = (1ull << lane) - 1ull;
        int s;
        if (fid)       s = id_idx[base_id + bid + __popcll(mid & below)];
        else if (fkos) s = 8192 + (k - 4) * 256 + kos_idx[base_kos + bkos + __popcll(mkos & below)];
        else           s = 8960 + k;
        sel2[idx] = s;
    }
}

// ---------------- Kernel 2: build Thi = bf16(relu(kindc[kind] + x @ W1)) ----------------
// rows: 0..8191 = enc_ids (kind 3); 8192..8959 = kos (kind 4+q>>8); 8960..8967 = zero src.
__global__ __launch_bounds__(512, 2) void table_kernel(const float* __restrict__ enc_ids,
                                                       const float* __restrict__ kos_emb,
                                                       const u16* __restrict__ Wt1,
                                                       const float* __restrict__ kindc,
                                                       u16* __restrict__ Thi) {
    __shared__ u16 sAhi[2][128 * 64];
    __shared__ u16 sAlo[2][128 * 64];
    __shared__ u16 sB[2][256 * 64];

    const int t = threadIdx.x;
    const int row0 = blockIdx.x * 128;
    const int col0 = blockIdx.y * 256;

    const int ar = t >> 2;
    const int ac = (t & 3) * 16;
    const int br = t >> 1;
    const int bc = (t & 1) * 32;

    const int arow = row0 + ar;
    const float* Arow;
    bool hasrc = true;
    if (arow < NUM_IDS)        Arow = &enc_ids[(size_t)arow * DD];
    else if (arow < 8960)      Arow = &kos_emb[(size_t)((arow - NUM_IDS) & 255) * DD];
    else { Arow = enc_ids; hasrc = false; }
    const u16* Brow = &Wt1[(size_t)(col0 + br) * DD];

    const int lane = t & 63;
    const int wid  = t >> 6;
    const int wr = wid >> 2, wc = wid & 3;
    const int lrow = lane & 15, lkg = lane >> 4;

    f32x4 acc[4][4];
    #pragma unroll
    for (int mi = 0; mi < 4; ++mi)
        #pragma unroll
        for (int ni = 0; ni < 4; ++ni)
            acc[mi][ni] = (f32x4){0.f, 0.f, 0.f, 0.f};

    f32x4 av[4];
    u16x8 bv[4];

    auto STAGE_ISSUE = [&](int kc) {
        const int kb = kc * 64;
        #pragma unroll
        for (int j = 0; j < 4; ++j)
            av[j] = hasrc ? *(const f32x4*)&Arow[kb + ac + j * 4] : (f32x4){0.f,0.f,0.f,0.f};
        #pragma unroll
        for (int j = 0; j < 4; ++j) bv[j] = *(const u16x8*)&Brow[kb + bc + j * 8];
    };

    auto WRITE = [&](int buf) {
        u16 hi[16], lo[16];
        #pragma unroll
        for (int j = 0; j < 4; ++j)
            #pragma unroll
            for (int e = 0; e < 4; ++e) {
                float r = av[j][e];
                u16 h = bf16bits(r);
                hi[j * 4 + e] = h;
                lo[j * 4 + e] = bf16bits(r - bf16tof(h));
            }
        const int abase = ar * 128;
        const int o0 = abase + ((ac * 2) ^ ((ar & 7) << 4));
        const int o1 = abase + ((ac * 2 + 16) ^ ((ar & 7) << 4));
        *(u16x8*)((char*)sAhi[buf] + o0) = *(const u16x8*)&hi[0];
        *(u16x8*)((char*)sAhi[buf] + o1) = *(const u16x8*)&hi[8];
        *(u16x8*)((char*)sAlo[buf] + o0) = *(const u16x8*)&lo[0];
        *(u16x8*)((char*)sAlo[buf] + o1) = *(const u16x8*)&lo[8];
        const int bbase = br * 128;
        #pragma unroll
        for (int j = 0; j < 4; ++j) {
            int off = bbase + ((bc * 2 + j * 16) ^ ((br & 7) << 4));
            *(u16x8*)((char*)sB[buf] + off) = bv[j];
        }
    };

    auto COMPUTE = [&](int buf) {
        #pragma unroll
        for (int ks = 0; ks < 2; ++ks) {
            s16x8 ah[4], al[4], bbf[4];
            #pragma unroll
            for (int mi = 0; mi < 4; ++mi) {
                int row = wr * 64 + mi * 16 + lrow;
                int off = row * 128 + ((ks * 64 + lkg * 16) ^ ((row & 7) << 4));
                ah[mi] = *(const s16x8*)((const char*)sAhi[buf] + off);
                al[mi] = *(const s16x8*)((const char*)sAlo[buf] + off);
            }
            #pragma unroll
            for (int ni = 0; ni < 4; ++ni) {
                int row = wc * 64 + ni * 16 + lrow;
                int off = row * 128 + ((ks * 64 + lkg * 16) ^ ((row & 7) << 4));
                bbf[ni] = *(const s16x8*)((const char*)sB[buf] + off);
            }
            #pragma unroll
            for (int mi = 0; mi < 4; ++mi)
                #pragma unroll
                for (int ni = 0; ni < 4; ++ni) {
                    acc[mi][ni] = __builtin_amdgcn_mfma_f32_16x16x32_bf16(ah[mi], bbf[ni], acc[mi][ni], 0, 0, 0);
                    acc[mi][ni] = __builtin_amdgcn_mfma_f32_16x16x32_bf16(al[mi], bbf[ni], acc[mi][ni], 0, 0, 0);
                }
        }
    };

    STAGE_ISSUE(0);
    WRITE(0);
    __syncthreads();
    int cur = 0;
    #pragma unroll 1
    for (int kc = 0; kc < 4; ++kc) {
        if (kc < 3) STAGE_ISSUE(kc + 1);
        COMPUTE(cur);
        if (kc < 3) WRITE(cur ^ 1);
        __syncthreads();
        cur ^= 1;
    }

    // epilogue: add kindc[kind(row)], relu, bf16, store
    #pragma unroll
    for (int ni = 0; ni < 4; ++ni) {
        int col = col0 + wc * 64 + ni * 16 + lrow;
        #pragma unroll
        for (int mi = 0; mi < 4; ++mi) {
            int rbase = row0 + wr * 64 + mi * 16 + lkg * 4;
            #pragma unroll
            for (int j = 0; j < 4; ++j) {
                int rg = rbase + j;
                int kind = (rg < NUM_IDS) ? 3
                         : (rg < 8960) ? 4 + ((rg - NUM_IDS) >> 8)
                         : (rg < 8968) ? (rg - 8960) : 0;
                float v = acc[mi][ni][j] + kindc[kind * EXPR_D + col];
                Thi[(size_t)rg * EXPR_D + col] = bf16bits(fmaxf(v, 0.f));
            }
        }
    }
}

// ---------------- Kernel 3: O = relu(Thi @ Wt^T + b2)  (table-level layer 2) ----------
// BM=128, BN=256, BK=32 (16 chunks), 512 threads (2x4 waves), dbuf LDS = 48 KiB.
__global__ __launch_bounds__(512, 4) void table2_kernel(const u16* __restrict__ Thi,
                                                        const u16* __restrict__ Wt,
                                                        const float* __restrict__ b2,
                                                        float* __restrict__ O) {
    __shared__ u16 sA[2][128 * 32];
    __shared__ u16 sB[2][256 * 32];

    const int t = threadIdx.x;
    const int row0 = blockIdx.x * 128;
    const int col0 = blockIdx.y * 256;

    const int ar = t >> 2;
    const int ac8 = (t & 3) * 8;
    const int br = t >> 1;
    const int bc16 = (t & 1) * 16;

    const u16* Arow = &Thi[(size_t)(row0 + ar) * EXPR_D + ac8];
    const u16* Brow = &Wt[(size_t)(col0 + br) * EXPR_D + bc16];

    const int lane = t & 63;
    const int wid  = t >> 6;
    const int wr = wid >> 2, wc = wid & 3;
    const int lrow = lane & 15, lkg = lane >> 4;

    f32x4 acc[4][4];
    #pragma unroll
    for (int mi = 0; mi < 4; ++mi)
        #pragma unroll
        for (int ni = 0; ni < 4; ++ni)
            acc[mi][ni] = (f32x4){0.f, 0.f, 0.f, 0.f};

    u16x8 av;
    u16x8 bv[2];

    auto STAGE_ISSUE = [&](int kc) {
        const int kb = kc * 32;
        av = *(const u16x8*)&Arow[kb];
        bv[0] = *(const u16x8*)&Brow[kb];
        bv[1] = *(const u16x8*)&Brow[kb + 8];
    };

    auto WRITE = [&](int buf) {
        int aoff = ar * 64 + ((ac8 * 2) ^ ((ar & 3) << 4));
        *(u16x8*)((char*)sA[buf] + aoff) = av;
        #pragma unroll
        for (int j = 0; j < 2; ++j) {
            int boff = br * 64 + ((bc16 * 2 + j * 16) ^ ((br & 3) << 4));
            *(u16x8*)((char*)sB[buf] + boff) = bv[j];
        }
    };

    auto COMPUTE = [&](int buf) {
        s16x8 a[4], b[4];
        #pragma unroll
        for (int mi = 0; mi < 4; ++mi) {
            int row = wr * 64 + mi * 16 + lrow;
            int off = row * 64 + ((lkg * 16) ^ ((row & 3) << 4));
            a[mi] = *(const s16x8*)((const char*)sA[buf] + off);
        }
        #pragma unroll
        for (int ni = 0; ni < 4; ++ni) {
            int row = wc * 64 + ni * 16 + lrow;
            int off = row * 64 + ((lkg * 16) ^ ((row & 3) << 4));
            b[ni] = *(const s16x8*)((const char*)sB[buf] + off);
        }
        #pragma unroll
        for (int mi = 0; mi < 4; ++mi)
            #pragma unroll
            for (int ni = 0; ni < 4; ++ni)
                acc[mi][ni] = __builtin_amdgcn_mfma_f32_16x16x32_bf16(a[mi], b[ni], acc[mi][ni], 0, 0, 0);
    };

    STAGE_ISSUE(0);
    WRITE(0);
    __syncthreads();
    int cur = 0;
    #pragma unroll 1
    for (int kc = 0; kc < 16; ++kc) {
        if (kc < 15) STAGE_ISSUE(kc + 1);
        COMPUTE(cur);
        if (kc < 15) WRITE(cur ^ 1);
        __syncthreads();
        cur ^= 1;
    }

    #pragma unroll
    for (int ni = 0; ni < 4; ++ni) {
        int col = col0 + wc * 64 + ni * 16 + lrow;
        float bias = b2[col];
        #pragma unroll
        for (int mi = 0; mi < 4; ++mi) {
            int rbase = row0 + wr * 64 + mi * 16 + lkg * 4;
            #pragma unroll
            for (int j = 0; j < 4; ++j)
                O[(size_t)(rbase + j) * EXPR_D + col] = fmaxf(acc[mi][ni][j] + bias, 0.f);
        }
    }
}

// ---------------- Kernel 4: out[pos] = O[sel2[pos]]  (pure gather-copy) ----------
// 4 waves/block, 16 positions/block; load ALL 8 f32x4 first (max MLP), then store all.
__global__ __launch_bounds__(256) void gather_kernel(const int* __restrict__ sel2,
                                                     const float* __restrict__ O,
                                                     float* __restrict__ out) {
    const int t = threadIdx.x;
    const int lane = t & 63, wave = t >> 6;
    const int base = blockIdx.x * 16;
    int rows[4];
    #pragma unroll
    for (int i = 0; i < 4; ++i) rows[i] = sel2[base + i * 4 + wave];
    f32x4 v0[4], v1[4];
    #pragma unroll
    for (int i = 0; i < 4; ++i) {
        const f32x4* src = (const f32x4*)&O[(size_t)rows[i] * EXPR_D];
        v0[i] = src[lane];
        v1[i] = src[lane + 64];
    }
    #pragma unroll
    for (int i = 0; i < 4; ++i) {
        const int pos = base + i * 4 + wave;
        f32x4* dst = (f32x4*)&out[(size_t)pos * EXPR_D];
        __builtin_nontemporal_store(v0[i], &dst[lane]);
        __builtin_nontemporal_store(v1[i], &dst[lane + 64]);
    }
}

extern "C" void kernel_launch(void* const* d_in, const int* in_sizes, int n_in,
                              void* d_out, int out_size, void* d_ws, size_t ws_size,
                              hipStream_t stream) {
    const int*   token_type = (const int*)d_in[0];
    const int*   kos_idx    = (const int*)d_in[1];
    const int*   id_idx     = (const int*)d_in[2];
    const float* enc_ids    = (const float*)d_in[3];
    const float* kind_emb   = (const float*)d_in[4];
    const float* kos_emb    = (const float*)d_in[5];
    const float* Wp         = (const float*)d_in[6];
    const float* bp         = (const float*)d_in[7];
    const float* W2         = (const float*)d_in[8];
    const float* b2         = (const float*)d_in[9];
    float* out = (float*)d_out;

    char* ws = (char*)d_ws;
    int*   sel2   = (int*)ws;                          // 256 KiB
    float* kindc  = (float*)(ws + 262144);             // 16 KiB
    u16*   Wt     = (u16*)(ws + 282624);               // 512 KiB
    u16*   Wt1    = (u16*)(ws + 806912);               // 256 KiB
    u16*   Thi    = (u16*)(ws + 1069056);              // TROWS*512*2 = 9306112
    float* O      = (float*)(ws + 10375168);           // TROWS*512*4 = 18612224 (~29 MB total)

    hipLaunchKernelGGL(prep_kernel, dim3(641), dim3(256), 0, stream,
                       W2, kind_emb, Wp, bp, token_type, kos_idx, id_idx,
                       Wt, Wt1, kindc, sel2);
    hipLaunchKernelGGL(table_kernel, dim3(TROWS / 128, EXPR_D / 256), dim3(512), 0, stream,
                       enc_ids, kos_emb, Wt1, kindc, Thi);
    hipLaunchKernelGGL(table2_kernel, dim3(TROWS / 128, EXPR_D / 256), dim3(512), 0, stream,
                       Thi, Wt, b2, O);
    hipLaunchKernelGGL(gather_kernel, dim3(NPOS / 16), dim3(256), 0, stream,
                       sel2, O, out);
}

// Round 12
// 76.841 us; speedup vs baseline: 1.3799x; 1.0589x over previous
//
#include <hip/hip_runtime.h>
#include <hip/hip_bf16.h>

#define BB 128
#define SS 512
#define NPOS (BB*SS)          // 65536
#define DD 256
#define KIND_D 8
#define EXPR_D 512
#define KOS_VOCAB 256
#define NUM_IDS 8192
#define IDENTIFIER_KIND 3
#define TROWS 9088            // padded table rows (8968 used) = 71*128 = 142*64

typedef unsigned short u16;
typedef __attribute__((ext_vector_type(8))) short s16x8;           // 8 bf16 (4 VGPRs)
typedef __attribute__((ext_vector_type(8))) unsigned short u16x8;  // 16B unit
typedef __attribute__((ext_vector_type(4))) float f32x4;

__device__ __forceinline__ u16 bf16bits(float v) {
    __hip_bfloat16 h = __float2bfloat16(v);
    return *(u16*)&h;
}
__device__ __forceinline__ float bf16tof(u16 b) {
    __hip_bfloat16 h = *(__hip_bfloat16*)&b;
    return __bfloat162float(h);
}

// ---------------- Kernel 1: prep ----------------
// blocks 0..255   : W2 [512k][512n] f32 -> Wt [n][k] bf16
// block  256      : kindc[kind][j] = kind_emb[kind] @ W_proj[0:8] + b_proj
// blocks 257..384 : W_proj[8:264] [256k][512n] f32 -> Wt1 [n][k] bf16
// blocks 385..640 : per-256-chunk {id,kos} counts of token_type -> blkcnt
__global__ __launch_bounds__(256) void prep_kernel(const float* __restrict__ W2,
                                                   const float* __restrict__ kind_emb,
                                                   const float* __restrict__ Wp,
                                                   const float* __restrict__ bp,
                                                   const int* __restrict__ token_type,
                                                   u16* __restrict__ Wt,
                                                   u16* __restrict__ Wt1,
                                                   float* __restrict__ kindc,
                                                   int2* __restrict__ blkcnt) {
    __shared__ float tile[32][33];
    __shared__ int swid[4], swkos[4];
    const int bi = blockIdx.x;
    const int t = threadIdx.x;

    if (bi < 256) {
        const int n0 = (bi & 15) * 32;
        const int k0 = (bi >> 4) * 32;
        const int lj = t & 31, li = t >> 5;
        #pragma unroll
        for (int p = 0; p < 4; ++p) {
            int i = li + p * 8;
            tile[i][lj] = W2[(size_t)(k0 + i) * EXPR_D + n0 + lj];
        }
        __syncthreads();
        #pragma unroll
        for (int p = 0; p < 4; ++p) {
            int j = li + p * 8;
            Wt[(size_t)(n0 + j) * EXPR_D + k0 + lj] = bf16bits(tile[lj][j]);
        }
    } else if (bi == 256) {
        #pragma unroll
        for (int rep = 0; rep < 2; ++rep) {
            int j = t + rep * 256;
            float bias = bp[j];
            for (int kind = 0; kind < 8; ++kind) {
                float a = bias;
                #pragma unroll
                for (int d = 0; d < KIND_D; ++d)
                    a = fmaf(kind_emb[kind * KIND_D + d], Wp[d * EXPR_D + j], a);
                kindc[kind * EXPR_D + j] = a;
            }
        }
    } else if (bi < 385) {
        const int idx = bi - 257;
        const int n0 = (idx & 15) * 32;
        const int k0 = (idx >> 4) * 32;
        const float* W1p = Wp + (size_t)KIND_D * EXPR_D;
        const int lj = t & 31, li = t >> 5;
        #pragma unroll
        for (int p = 0; p < 4; ++p) {
            int i = li + p * 8;
            tile[i][lj] = W1p[(size_t)(k0 + i) * EXPR_D + n0 + lj];
        }
        __syncthreads();
        #pragma unroll
        for (int p = 0; p < 4; ++p) {
            int j = li + p * 8;
            Wt1[(size_t)(n0 + j) * DD + k0 + lj] = bf16bits(tile[lj][j]);
        }
    } else {
        const int blk = bi - 385;
        const int lane = t & 63, wave = t >> 6;
        int k = token_type[blk * 256 + t];
        unsigned long long mid  = __ballot(k == IDENTIFIER_KIND);
        unsigned long long mkos = __ballot(k >= 4 && k <= 6);
        if (lane == 0) { swid[wave] = __popcll(mid); swkos[wave] = __popcll(mkos); }
        __syncthreads();
        if (t == 0) {
            int a = 0, c = 0;
            #pragma unroll
            for (int w = 0; w < 4; ++w) { a += swid[w]; c += swkos[w]; }
            blkcnt[blk] = make_int2(a, c);
        }
    }
}

// ---------------- Kernel 2: scatter -> sel2[] (direct table-row index) ----------------
// id rows: 0..8191 ; kos rows: 8192 + (kind-4)*256 + kos_idx ; none: 8960 + kind
__global__ __launch_bounds__(256) void scatter_kernel(const int* __restrict__ token_type,
                                                      const int2* __restrict__ blkcnt,
                                                      const int* __restrict__ kos_idx,
                                                      const int* __restrict__ id_idx,
                                                      int* __restrict__ sel2) {
    __shared__ int2 sbase;
    __shared__ int swid[4], swkos[4];
    const int b = blockIdx.x, t = threadIdx.x;
    const int lane = t & 63, wave = t >> 6;
    if (t < 64) {
        int a = 0, c = 0;
        for (int i = t; i < b; i += 64) { int2 v = blkcnt[i]; a += v.x; c += v.y; }
        #pragma unroll
        for (int off = 32; off; off >>= 1) { a += __shfl_down(a, off); c += __shfl_down(c, off); }
        if (t == 0) sbase = make_int2(a, c);
    }
    const int idx = b * 256 + t;
    const int k = token_type[idx];
    const bool fid  = (k == IDENTIFIER_KIND);
    const bool fkos = (k >= 4 && k <= 6);
    unsigned long long mid  = __ballot(fid);
    unsigned long long mkos = __ballot(fkos);
    if (lane == 0) { swid[wave] = __popcll(mid); swkos[wave] = __popcll(mkos); }
    __syncthreads();
    int bid = 0, bkos = 0;
    for (int w = 0; w < wave; ++w) { bid += swid[w]; bkos += swkos[w]; }
    unsigned long long below = (1ull << lane) - 1ull;
    int s;
    if (fid)       s = id_idx[sbase.x + bid + __popcll(mid & below)];
    else if (fkos) s = 8192 + (k - 4) * 256 + kos_idx[sbase.y + bkos + __popcll(mkos & below)];
    else           s = 8960 + k;
    sel2[idx] = s;
}

// ---------------- Kernel 3: build Thi = bf16(relu(kindc[kind] + x @ W1)) ----------------
// rows: 0..8191 = enc_ids (kind 3); 8192..8959 = kos (kind 4+q>>8); 8960..8967 = zero src.
__global__ __launch_bounds__(512, 2) void table_kernel(const float* __restrict__ enc_ids,
                                                       const float* __restrict__ kos_emb,
                                                       const u16* __restrict__ Wt1,
                                                       const float* __restrict__ kindc,
                                                       u16* __restrict__ Thi) {
    __shared__ u16 sAhi[2][128 * 64];
    __shared__ u16 sAlo[2][128 * 64];
    __shared__ u16 sB[2][256 * 64];

    const int t = threadIdx.x;
    const int row0 = blockIdx.x * 128;
    const int col0 = blockIdx.y * 256;

    const int ar = t >> 2;
    const int ac = (t & 3) * 16;
    const int br = t >> 1;
    const int bc = (t & 1) * 32;

    const int arow = row0 + ar;
    const float* Arow;
    bool hasrc = true;
    if (arow < NUM_IDS)        Arow = &enc_ids[(size_t)arow * DD];
    else if (arow < 8960)      Arow = &kos_emb[(size_t)((arow - NUM_IDS) & 255) * DD];
    else { Arow = enc_ids; hasrc = false; }
    const u16* Brow = &Wt1[(size_t)(col0 + br) * DD];

    const int lane = t & 63;
    const int wid  = t >> 6;
    const int wr = wid >> 2, wc = wid & 3;
    const int lrow = lane & 15, lkg = lane >> 4;

    f32x4 acc[4][4];
    #pragma unroll
    for (int mi = 0; mi < 4; ++mi)
        #pragma unroll
        for (int ni = 0; ni < 4; ++ni)
            acc[mi][ni] = (f32x4){0.f, 0.f, 0.f, 0.f};

    f32x4 av[4];
    u16x8 bv[4];

    auto STAGE_ISSUE = [&](int kc) {
        const int kb = kc * 64;
        #pragma unroll
        for (int j = 0; j < 4; ++j)
            av[j] = hasrc ? *(const f32x4*)&Arow[kb + ac + j * 4] : (f32x4){0.f,0.f,0.f,0.f};
        #pragma unroll
        for (int j = 0; j < 4; ++j) bv[j] = *(const u16x8*)&Brow[kb + bc + j * 8];
    };

    auto WRITE = [&](int buf) {
        u16 hi[16], lo[16];
        #pragma unroll
        for (int j = 0; j < 4; ++j)
            #pragma unroll
            for (int e = 0; e < 4; ++e) {
                float r = av[j][e];
                u16 h = bf16bits(r);
                hi[j * 4 + e] = h;
                lo[j * 4 + e] = bf16bits(r - bf16tof(h));
            }
        const int abase = ar * 128;
        const int o0 = abase + ((ac * 2) ^ ((ar & 7) << 4));
        const int o1 = abase + ((ac * 2 + 16) ^ ((ar & 7) << 4));
        *(u16x8*)((char*)sAhi[buf] + o0) = *(const u16x8*)&hi[0];
        *(u16x8*)((char*)sAhi[buf] + o1) = *(const u16x8*)&hi[8];
        *(u16x8*)((char*)sAlo[buf] + o0) = *(const u16x8*)&lo[0];
        *(u16x8*)((char*)sAlo[buf] + o1) = *(const u16x8*)&lo[8];
        const int bbase = br * 128;
        #pragma unroll
        for (int j = 0; j < 4; ++j) {
            int off = bbase + ((bc * 2 + j * 16) ^ ((br & 7) << 4));
            *(u16x8*)((char*)sB[buf] + off) = bv[j];
        }
    };

    auto COMPUTE = [&](int buf) {
        #pragma unroll
        for (int ks = 0; ks < 2; ++ks) {
            s16x8 ah[4], al[4], bbf[4];
            #pragma unroll
            for (int mi = 0; mi < 4; ++mi) {
                int row = wr * 64 + mi * 16 + lrow;
                int off = row * 128 + ((ks * 64 + lkg * 16) ^ ((row & 7) << 4));
                ah[mi] = *(const s16x8*)((const char*)sAhi[buf] + off);
                al[mi] = *(const s16x8*)((const char*)sAlo[buf] + off);
            }
            #pragma unroll
            for (int ni = 0; ni < 4; ++ni) {
                int row = wc * 64 + ni * 16 + lrow;
                int off = row * 128 + ((ks * 64 + lkg * 16) ^ ((row & 7) << 4));
                bbf[ni] = *(const s16x8*)((const char*)sB[buf] + off);
            }
            #pragma unroll
            for (int mi = 0; mi < 4; ++mi)
                #pragma unroll
                for (int ni = 0; ni < 4; ++ni) {
                    acc[mi][ni] = __builtin_amdgcn_mfma_f32_16x16x32_bf16(ah[mi], bbf[ni], acc[mi][ni], 0, 0, 0);
                    acc[mi][ni] = __builtin_amdgcn_mfma_f32_16x16x32_bf16(al[mi], bbf[ni], acc[mi][ni], 0, 0, 0);
                }
        }
    };

    STAGE_ISSUE(0);
    WRITE(0);
    __syncthreads();
    int cur = 0;
    #pragma unroll 1
    for (int kc = 0; kc < 4; ++kc) {
        if (kc < 3) STAGE_ISSUE(kc + 1);
        COMPUTE(cur);
        if (kc < 3) WRITE(cur ^ 1);
        __syncthreads();
        cur ^= 1;
    }

    // epilogue: add kindc[kind(row)], relu, bf16, store
    #pragma unroll
    for (int ni = 0; ni < 4; ++ni) {
        int col = col0 + wc * 64 + ni * 16 + lrow;
        #pragma unroll
        for (int mi = 0; mi < 4; ++mi) {
            int rbase = row0 + wr * 64 + mi * 16 + lkg * 4;
            #pragma unroll
            for (int j = 0; j < 4; ++j) {
                int rg = rbase + j;
                int kind = (rg < NUM_IDS) ? 3
                         : (rg < 8960) ? 4 + ((rg - NUM_IDS) >> 8)
                         : (rg < 8968) ? (rg - 8960) : 0;
                float v = acc[mi][ni][j] + kindc[kind * EXPR_D + col];
                Thi[(size_t)rg * EXPR_D + col] = bf16bits(fmaxf(v, 0.f));
            }
        }
    }
}

// ---------------- Kernel 4: O = relu(Thi @ Wt^T + b2)  (table-level layer 2) ----------
// BM=64, BN=256, BK=32 (16 chunks, same K-order), 512 threads (2x4 waves).
// Grid (142, 2) = 284 blocks -> full CU coverage. dbuf LDS = 40 KiB. f32 output.
__global__ __launch_bounds__(512, 4) void table2_kernel(const u16* __restrict__ Thi,
                                                        const u16* __restrict__ Wt,
                                                        const float* __restrict__ b2,
                                                        float* __restrict__ O) {
    __shared__ u16 sA[2][64 * 32];    // 4 KiB each
    __shared__ u16 sB[2][256 * 32];   // 16 KiB each

    const int t = threadIdx.x;
    const int row0 = blockIdx.x * 64;
    const int col0 = blockIdx.y * 256;

    const bool doA = (t < 256);
    const int ar = (t & 255) >> 2;    // 0..63
    const int ac8 = (t & 3) * 8;
    const int br = t >> 1;            // 0..255
    const int bc16 = (t & 1) * 16;

    const u16* Arow = &Thi[(size_t)(row0 + ar) * EXPR_D + ac8];
    const u16* Brow = &Wt[(size_t)(col0 + br) * EXPR_D + bc16];

    const int lane = t & 63;
    const int wid  = t >> 6;
    const int wr = wid >> 2, wc = wid & 3;   // wave covers rows wr*32..+32, cols wc*64..+64
    const int lrow = lane & 15, lkg = lane >> 4;

    f32x4 acc[2][4];
    #pragma unroll
    for (int mi = 0; mi < 2; ++mi)
        #pragma unroll
        for (int ni = 0; ni < 4; ++ni)
            acc[mi][ni] = (f32x4){0.f, 0.f, 0.f, 0.f};

    u16x8 av;
    u16x8 bv[2];

    auto STAGE_ISSUE = [&](int kc) {
        const int kb = kc * 32;
        if (doA) av = *(const u16x8*)&Arow[kb];
        bv[0] = *(const u16x8*)&Brow[kb];
        bv[1] = *(const u16x8*)&Brow[kb + 8];
    };

    auto WRITE = [&](int buf) {
        if (doA) {
            int aoff = ar * 64 + ((ac8 * 2) ^ ((ar & 3) << 4));
            *(u16x8*)((char*)sA[buf] + aoff) = av;
        }
        #pragma unroll
        for (int j = 0; j < 2; ++j) {
            int boff = br * 64 + ((bc16 * 2 + j * 16) ^ ((br & 3) << 4));
            *(u16x8*)((char*)sB[buf] + boff) = bv[j];
        }
    };

    auto COMPUTE = [&](int buf) {
        s16x8 a[2], b[4];
        #pragma unroll
        for (int mi = 0; mi < 2; ++mi) {
            int row = wr * 32 + mi * 16 + lrow;
            int off = row * 64 + ((lkg * 16) ^ ((row & 3) << 4));
            a[mi] = *(const s16x8*)((const char*)sA[buf] + off);
        }
        #pragma unroll
        for (int ni = 0; ni < 4; ++ni) {
            int row = wc * 64 + ni * 16 + lrow;
            int off = row * 64 + ((lkg * 16) ^ ((row & 3) << 4));
            b[ni] = *(const s16x8*)((const char*)sB[buf] + off);
        }
        #pragma unroll
        for (int mi = 0; mi < 2; ++mi)
            #pragma unroll
            for (int ni = 0; ni < 4; ++ni)
                acc[mi][ni] = __builtin_amdgcn_mfma_f32_16x16x32_bf16(a[mi], b[ni], acc[mi][ni], 0, 0, 0);
    };

    STAGE_ISSUE(0);
    WRITE(0);
    __syncthreads();
    int cur = 0;
    #pragma unroll 1
    for (int kc = 0; kc < 16; ++kc) {
        if (kc < 15) STAGE_ISSUE(kc + 1);
        COMPUTE(cur);
        if (kc < 15) WRITE(cur ^ 1);
        __syncthreads();
        cur ^= 1;
    }

    #pragma unroll
    for (int ni = 0; ni < 4; ++ni) {
        int col = col0 + wc * 64 + ni * 16 + lrow;
        float bias = b2[col];
        #pragma unroll
        for (int mi = 0; mi < 2; ++mi) {
            int rbase = row0 + wr * 32 + mi * 16 + lkg * 4;
            #pragma unroll
            for (int j = 0; j < 4; ++j)
                O[(size_t)(rbase + j) * EXPR_D + col] = fmaxf(acc[mi][ni][j] + bias, 0.f);
        }
    }
}

// ---------------- Kernel 5: out[pos] = O[sel2[pos]]  (pure gather-copy) ----------
// 4 waves/block, 16 positions/block; load ALL 8 f32x4 first (max MLP), then store all.
__global__ __launch_bounds__(256) void gather_kernel(const int* __restrict__ sel2,
                                                     const float* __restrict__ O,
                                                     float* __restrict__ out) {
    const int t = threadIdx.x;
    const int lane = t & 63, wave = t >> 6;
    const int base = blockIdx.x * 16;
    int rows[4];
    #pragma unroll
    for (int i = 0; i < 4; ++i) rows[i] = sel2[base + i * 4 + wave];
    f32x4 v0[4], v1[4];
    #pragma unroll
    for (int i = 0; i < 4; ++i) {
        const f32x4* src = (const f32x4*)&O[(size_t)rows[i] * EXPR_D];
        v0[i] = src[lane];
        v1[i] = src[lane + 64];
    }
    #pragma unroll
    for (int i = 0; i < 4; ++i) {
        const int pos = base + i * 4 + wave;
        f32x4* dst = (f32x4*)&out[(size_t)pos * EXPR_D];
        __builtin_nontemporal_store(v0[i], &dst[lane]);
        __builtin_nontemporal_store(v1[i], &dst[lane + 64]);
    }
}

extern "C" void kernel_launch(void* const* d_in, const int* in_sizes, int n_in,
                              void* d_out, int out_size, void* d_ws, size_t ws_size,
                              hipStream_t stream) {
    const int*   token_type = (const int*)d_in[0];
    const int*   kos_idx    = (const int*)d_in[1];
    const int*   id_idx     = (const int*)d_in[2];
    const float* enc_ids    = (const float*)d_in[3];
    const float* kind_emb   = (const float*)d_in[4];
    const float* kos_emb    = (const float*)d_in[5];
    const float* Wp         = (const float*)d_in[6];
    const float* bp         = (const float*)d_in[7];
    const float* W2         = (const float*)d_in[8];
    const float* b2         = (const float*)d_in[9];
    float* out = (float*)d_out;

    char* ws = (char*)d_ws;
    int*   sel2   = (int*)ws;                          // 256 KiB
    float* kindc  = (float*)(ws + 262144);             // 16 KiB
    int2*  blkcnt = (int2*)(ws + 278528);              // 4 KiB
    u16*   Wt     = (u16*)(ws + 282624);               // 512 KiB
    u16*   Wt1    = (u16*)(ws + 806912);               // 256 KiB
    u16*   Thi    = (u16*)(ws + 1069056);              // TROWS*512*2 = 9306112
    float* O      = (float*)(ws + 10375168);           // TROWS*512*4 = 18612224 (~29 MB total)

    hipLaunchKernelGGL(prep_kernel, dim3(641), dim3(256), 0, stream,
                       W2, kind_emb, Wp, bp, token_type, Wt, Wt1, kindc, blkcnt);
    hipLaunchKernelGGL(scatter_kernel, dim3(256), dim3(256), 0, stream,
                       token_type, blkcnt, kos_idx, id_idx, sel2);
    hipLaunchKernelGGL(table_kernel, dim3(TROWS / 128, EXPR_D / 256), dim3(512), 0, stream,
                       enc_ids, kos_emb, Wt1, kindc, Thi);
    hipLaunchKernelGGL(table2_kernel, dim3(TROWS / 64, EXPR_D / 256), dim3(512), 0, stream,
                       Thi, Wt, b2, O);
    hipLaunchKernelGGL(gather_kernel, dim3(NPOS / 16), dim3(256), 0, stream,
                       sel2, O, out);
}

// Round 13
// 75.721 us; speedup vs baseline: 1.4003x; 1.0148x over previous
//
#include <hip/hip_runtime.h>
#include <hip/hip_bf16.h>

#define BB 128
#define SS 512
#define NPOS (BB*SS)          // 65536
#define DD 256
#define KIND_D 8
#define EXPR_D 512
#define KOS_VOCAB 256
#define NUM_IDS 8192
#define IDENTIFIER_KIND 3
#define TROWS 9088            // padded table rows (8968 used) = 71*128

typedef unsigned short u16;
typedef __attribute__((ext_vector_type(8))) short s16x8;           // 8 bf16 (4 VGPRs)
typedef __attribute__((ext_vector_type(8))) unsigned short u16x8;  // 16B unit
typedef __attribute__((ext_vector_type(4))) float f32x4;

__device__ __forceinline__ u16 bf16bits(float v) {
    __hip_bfloat16 h = __float2bfloat16(v);
    return *(u16*)&h;
}
__device__ __forceinline__ float bf16tof(u16 b) {
    __hip_bfloat16 h = *(__hip_bfloat16*)&b;
    return __bfloat162float(h);
}

// ---------------- Kernel 1: prep ----------------
// blocks 0..255   : W2 [512k][512n] f32 -> Wt [n][k] bf16
// block  256      : kindc[kind][j] = kind_emb[kind] @ W_proj[0:8] + b_proj
// blocks 257..384 : W_proj[8:264] [256k][512n] f32 -> Wt1 [n][k] bf16
// blocks 385..640 : per-256-chunk {id,kos} counts of token_type -> blkcnt
__global__ __launch_bounds__(256) void prep_kernel(const float* __restrict__ W2,
                                                   const float* __restrict__ kind_emb,
                                                   const float* __restrict__ Wp,
                                                   const float* __restrict__ bp,
                                                   const int* __restrict__ token_type,
                                                   u16* __restrict__ Wt,
                                                   u16* __restrict__ Wt1,
                                                   float* __restrict__ kindc,
                                                   int2* __restrict__ blkcnt) {
    __shared__ float tile[32][33];
    __shared__ int swid[4], swkos[4];
    const int bi = blockIdx.x;
    const int t = threadIdx.x;

    if (bi < 256) {
        const int n0 = (bi & 15) * 32;
        const int k0 = (bi >> 4) * 32;
        const int lj = t & 31, li = t >> 5;
        #pragma unroll
        for (int p = 0; p < 4; ++p) {
            int i = li + p * 8;
            tile[i][lj] = W2[(size_t)(k0 + i) * EXPR_D + n0 + lj];
        }
        __syncthreads();
        #pragma unroll
        for (int p = 0; p < 4; ++p) {
            int j = li + p * 8;
            Wt[(size_t)(n0 + j) * EXPR_D + k0 + lj] = bf16bits(tile[lj][j]);
        }
    } else if (bi == 256) {
        #pragma unroll
        for (int rep = 0; rep < 2; ++rep) {
            int j = t + rep * 256;
            float bias = bp[j];
            for (int kind = 0; kind < 8; ++kind) {
                float a = bias;
                #pragma unroll
                for (int d = 0; d < KIND_D; ++d)
                    a = fmaf(kind_emb[kind * KIND_D + d], Wp[d * EXPR_D + j], a);
                kindc[kind * EXPR_D + j] = a;
            }
        }
    } else if (bi < 385) {
        const int idx = bi - 257;
        const int n0 = (idx & 15) * 32;
        const int k0 = (idx >> 4) * 32;
        const float* W1p = Wp + (size_t)KIND_D * EXPR_D;
        const int lj = t & 31, li = t >> 5;
        #pragma unroll
        for (int p = 0; p < 4; ++p) {
            int i = li + p * 8;
            tile[i][lj] = W1p[(size_t)(k0 + i) * EXPR_D + n0 + lj];
        }
        __syncthreads();
        #pragma unroll
        for (int p = 0; p < 4; ++p) {
            int j = li + p * 8;
            Wt1[(size_t)(n0 + j) * DD + k0 + lj] = bf16bits(tile[lj][j]);
        }
    } else {
        const int blk = bi - 385;
        const int lane = t & 63, wave = t >> 6;
        int k = token_type[blk * 256 + t];
        unsigned long long mid  = __ballot(k == IDENTIFIER_KIND);
        unsigned long long mkos = __ballot(k >= 4 && k <= 6);
        if (lane == 0) { swid[wave] = __popcll(mid); swkos[wave] = __popcll(mkos); }
        __syncthreads();
        if (t == 0) {
            int a = 0, c = 0;
            #pragma unroll
            for (int w = 0; w < 4; ++w) { a += swid[w]; c += swkos[w]; }
            blkcnt[blk] = make_int2(a, c);
        }
    }
}

// ---------------- Kernel 2: scatter -> sel2[] (direct table-row index) ----------------
// id rows: 0..8191 ; kos rows: 8192 + (kind-4)*256 + kos_idx ; none: 8960 + kind
__global__ __launch_bounds__(256) void scatter_kernel(const int* __restrict__ token_type,
                                                      const int2* __restrict__ blkcnt,
                                                      const int* __restrict__ kos_idx,
                                                      const int* __restrict__ id_idx,
                                                      int* __restrict__ sel2) {
    __shared__ int2 sbase;
    __shared__ int swid[4], swkos[4];
    const int b = blockIdx.x, t = threadIdx.x;
    const int lane = t & 63, wave = t >> 6;
    if (t < 64) {
        int a = 0, c = 0;
        for (int i = t; i < b; i += 64) { int2 v = blkcnt[i]; a += v.x; c += v.y; }
        #pragma unroll
        for (int off = 32; off; off >>= 1) { a += __shfl_down(a, off); c += __shfl_down(c, off); }
        if (t == 0) sbase = make_int2(a, c);
    }
    const int idx = b * 256 + t;
    const int k = token_type[idx];
    const bool fid  = (k == IDENTIFIER_KIND);
    const bool fkos = (k >= 4 && k <= 6);
    unsigned long long mid  = __ballot(fid);
    unsigned long long mkos = __ballot(fkos);
    if (lane == 0) { swid[wave] = __popcll(mid); swkos[wave] = __popcll(mkos); }
    __syncthreads();
    int bid = 0, bkos = 0;
    for (int w = 0; w < wave; ++w) { bid += swid[w]; bkos += swkos[w]; }
    unsigned long long below = (1ull << lane) - 1ull;
    int s;
    if (fid)       s = id_idx[sbase.x + bid + __popcll(mid & below)];
    else if (fkos) s = 8192 + (k - 4) * 256 + kos_idx[sbase.y + bkos + __popcll(mkos & below)];
    else           s = 8960 + k;
    sel2[idx] = s;
}

// ---------------- Kernel 3: build Thi = bf16(relu(kindc[kind] + x @ W1)) ----------------
// rows: 0..8191 = enc_ids (kind 3); 8192..8959 = kos (kind 4+q>>8); 8960..8967 = zero src.
__global__ __launch_bounds__(512, 2) void table_kernel(const float* __restrict__ enc_ids,
                                                       const float* __restrict__ kos_emb,
                                                       const u16* __restrict__ Wt1,
                                                       const float* __restrict__ kindc,
                                                       u16* __restrict__ Thi) {
    __shared__ u16 sAhi[2][128 * 64];
    __shared__ u16 sAlo[2][128 * 64];
    __shared__ u16 sB[2][256 * 64];

    const int t = threadIdx.x;
    const int row0 = blockIdx.x * 128;
    const int col0 = blockIdx.y * 256;

    const int ar = t >> 2;
    const int ac = (t & 3) * 16;
    const int br = t >> 1;
    const int bc = (t & 1) * 32;

    const int arow = row0 + ar;
    const float* Arow;
    bool hasrc = true;
    if (arow < NUM_IDS)        Arow = &enc_ids[(size_t)arow * DD];
    else if (arow < 8960)      Arow = &kos_emb[(size_t)((arow - NUM_IDS) & 255) * DD];
    else { Arow = enc_ids; hasrc = false; }
    const u16* Brow = &Wt1[(size_t)(col0 + br) * DD];

    const int lane = t & 63;
    const int wid  = t >> 6;
    const int wr = wid >> 2, wc = wid & 3;
    const int lrow = lane & 15, lkg = lane >> 4;

    f32x4 acc[4][4];
    #pragma unroll
    for (int mi = 0; mi < 4; ++mi)
        #pragma unroll
        for (int ni = 0; ni < 4; ++ni)
            acc[mi][ni] = (f32x4){0.f, 0.f, 0.f, 0.f};

    f32x4 av[4];
    u16x8 bv[4];

    auto STAGE_ISSUE = [&](int kc) {
        const int kb = kc * 64;
        #pragma unroll
        for (int j = 0; j < 4; ++j)
            av[j] = hasrc ? *(const f32x4*)&Arow[kb + ac + j * 4] : (f32x4){0.f,0.f,0.f,0.f};
        #pragma unroll
        for (int j = 0; j < 4; ++j) bv[j] = *(const u16x8*)&Brow[kb + bc + j * 8];
    };

    auto WRITE = [&](int buf) {
        u16 hi[16], lo[16];
        #pragma unroll
        for (int j = 0; j < 4; ++j)
            #pragma unroll
            for (int e = 0; e < 4; ++e) {
                float r = av[j][e];
                u16 h = bf16bits(r);
                hi[j * 4 + e] = h;
                lo[j * 4 + e] = bf16bits(r - bf16tof(h));
            }
        const int abase = ar * 128;
        const int o0 = abase + ((ac * 2) ^ ((ar & 7) << 4));
        const int o1 = abase + ((ac * 2 + 16) ^ ((ar & 7) << 4));
        *(u16x8*)((char*)sAhi[buf] + o0) = *(const u16x8*)&hi[0];
        *(u16x8*)((char*)sAhi[buf] + o1) = *(const u16x8*)&hi[8];
        *(u16x8*)((char*)sAlo[buf] + o0) = *(const u16x8*)&lo[0];
        *(u16x8*)((char*)sAlo[buf] + o1) = *(const u16x8*)&lo[8];
        const int bbase = br * 128;
        #pragma unroll
        for (int j = 0; j < 4; ++j) {
            int off = bbase + ((bc * 2 + j * 16) ^ ((br & 7) << 4));
            *(u16x8*)((char*)sB[buf] + off) = bv[j];
        }
    };

    auto COMPUTE = [&](int buf) {
        #pragma unroll
        for (int ks = 0; ks < 2; ++ks) {
            s16x8 ah[4], al[4], bbf[4];
            #pragma unroll
            for (int mi = 0; mi < 4; ++mi) {
                int row = wr * 64 + mi * 16 + lrow;
                int off = row * 128 + ((ks * 64 + lkg * 16) ^ ((row & 7) << 4));
                ah[mi] = *(const s16x8*)((const char*)sAhi[buf] + off);
                al[mi] = *(const s16x8*)((const char*)sAlo[buf] + off);
            }
            #pragma unroll
            for (int ni = 0; ni < 4; ++ni) {
                int row = wc * 64 + ni * 16 + lrow;
                int off = row * 128 + ((ks * 64 + lkg * 16) ^ ((row & 7) << 4));
                bbf[ni] = *(const s16x8*)((const char*)sB[buf] + off);
            }
            #pragma unroll
            for (int mi = 0; mi < 4; ++mi)
                #pragma unroll
                for (int ni = 0; ni < 4; ++ni) {
                    acc[mi][ni] = __builtin_amdgcn_mfma_f32_16x16x32_bf16(ah[mi], bbf[ni], acc[mi][ni], 0, 0, 0);
                    acc[mi][ni] = __builtin_amdgcn_mfma_f32_16x16x32_bf16(al[mi], bbf[ni], acc[mi][ni], 0, 0, 0);
                }
        }
    };

    STAGE_ISSUE(0);
    WRITE(0);
    __syncthreads();
    int cur = 0;
    #pragma unroll 1
    for (int kc = 0; kc < 4; ++kc) {
        if (kc < 3) STAGE_ISSUE(kc + 1);
        COMPUTE(cur);
        if (kc < 3) WRITE(cur ^ 1);
        __syncthreads();
        cur ^= 1;
    }

    // epilogue: add kindc[kind(row)], relu, bf16, store
    #pragma unroll
    for (int ni = 0; ni < 4; ++ni) {
        int col = col0 + wc * 64 + ni * 16 + lrow;
        #pragma unroll
        for (int mi = 0; mi < 4; ++mi) {
            int rbase = row0 + wr * 64 + mi * 16 + lkg * 4;
            #pragma unroll
            for (int j = 0; j < 4; ++j) {
                int rg = rbase + j;
                int kind = (rg < NUM_IDS) ? 3
                         : (rg < 8960) ? 4 + ((rg - NUM_IDS) >> 8)
                         : (rg < 8968) ? (rg - 8960) : 0;
                float v = acc[mi][ni][j] + kindc[kind * EXPR_D + col];
                Thi[(size_t)rg * EXPR_D + col] = bf16bits(fmaxf(v, 0.f));
            }
        }
    }
}

// ---------------- Kernel 4: O = relu(Thi @ Wt^T + b2)  (table-level layer 2) ----------
// BM=128, BN=256, BK=32 (16 chunks), 512 threads (2x4 waves), dbuf LDS = 48 KiB.
__global__ __launch_bounds__(512, 4) void table2_kernel(const u16* __restrict__ Thi,
                                                        const u16* __restrict__ Wt,
                                                        const float* __restrict__ b2,
                                                        float* __restrict__ O) {
    __shared__ u16 sA[2][128 * 32];
    __shared__ u16 sB[2][256 * 32];

    const int t = threadIdx.x;
    const int row0 = blockIdx.x * 128;
    const int col0 = blockIdx.y * 256;

    const int ar = t >> 2;
    const int ac8 = (t & 3) * 8;
    const int br = t >> 1;
    const int bc16 = (t & 1) * 16;

    const u16* Arow = &Thi[(size_t)(row0 + ar) * EXPR_D + ac8];
    const u16* Brow = &Wt[(size_t)(col0 + br) * EXPR_D + bc16];

    const int lane = t & 63;
    const int wid  = t >> 6;
    const int wr = wid >> 2, wc = wid & 3;
    const int lrow = lane & 15, lkg = lane >> 4;

    f32x4 acc[4][4];
    #pragma unroll
    for (int mi = 0; mi < 4; ++mi)
        #pragma unroll
        for (int ni = 0; ni < 4; ++ni)
            acc[mi][ni] = (f32x4){0.f, 0.f, 0.f, 0.f};

    u16x8 av;
    u16x8 bv[2];

    auto STAGE_ISSUE = [&](int kc) {
        const int kb = kc * 32;
        av = *(const u16x8*)&Arow[kb];
        bv[0] = *(const u16x8*)&Brow[kb];
        bv[1] = *(const u16x8*)&Brow[kb + 8];
    };

    auto WRITE = [&](int buf) {
        int aoff = ar * 64 + ((ac8 * 2) ^ ((ar & 3) << 4));
        *(u16x8*)((char*)sA[buf] + aoff) = av;
        #pragma unroll
        for (int j = 0; j < 2; ++j) {
            int boff = br * 64 + ((bc16 * 2 + j * 16) ^ ((br & 3) << 4));
            *(u16x8*)((char*)sB[buf] + boff) = bv[j];
        }
    };

    auto COMPUTE = [&](int buf) {
        s16x8 a[4], b[4];
        #pragma unroll
        for (int mi = 0; mi < 4; ++mi) {
            int row = wr * 64 + mi * 16 + lrow;
            int off = row * 64 + ((lkg * 16) ^ ((row & 3) << 4));
            a[mi] = *(const s16x8*)((const char*)sA[buf] + off);
        }
        #pragma unroll
        for (int ni = 0; ni < 4; ++ni) {
            int row = wc * 64 + ni * 16 + lrow;
            int off = row * 64 + ((lkg * 16) ^ ((row & 3) << 4));
            b[ni] = *(const s16x8*)((const char*)sB[buf] + off);
        }
        #pragma unroll
        for (int mi = 0; mi < 4; ++mi)
            #pragma unroll
            for (int ni = 0; ni < 4; ++ni)
                acc[mi][ni] = __builtin_amdgcn_mfma_f32_16x16x32_bf16(a[mi], b[ni], acc[mi][ni], 0, 0, 0);
    };

    STAGE_ISSUE(0);
    WRITE(0);
    __syncthreads();
    int cur = 0;
    #pragma unroll 1
    for (int kc = 0; kc < 16; ++kc) {
        if (kc < 15) STAGE_ISSUE(kc + 1);
        COMPUTE(cur);
        if (kc < 15) WRITE(cur ^ 1);
        __syncthreads();
        cur ^= 1;
    }

    #pragma unroll
    for (int ni = 0; ni < 4; ++ni) {
        int col = col0 + wc * 64 + ni * 16 + lrow;
        float bias = b2[col];
        #pragma unroll
        for (int mi = 0; mi < 4; ++mi) {
            int rbase = row0 + wr * 64 + mi * 16 + lkg * 4;
            #pragma unroll
            for (int j = 0; j < 4; ++j)
                O[(size_t)(rbase + j) * EXPR_D + col] = fmaxf(acc[mi][ni][j] + bias, 0.f);
        }
    }
}

// ---------------- Kernel 5: out[pos] = O[sel2[pos]]  (pure gather-copy) ----------
// 4 waves/block, 16 positions/block; load ALL 8 f32x4 first (max MLP), then store all.
__global__ __launch_bounds__(256) void gather_kernel(const int* __restrict__ sel2,
                                                     const float* __restrict__ O,
                                                     float* __restrict__ out) {
    const int t = threadIdx.x;
    const int lane = t & 63, wave = t >> 6;
    const int base = blockIdx.x * 16;
    int rows[4];
    #pragma unroll
    for (int i = 0; i < 4; ++i) rows[i] = sel2[base + i * 4 + wave];
    f32x4 v0[4], v1[4];
    #pragma unroll
    for (int i = 0; i < 4; ++i) {
        const f32x4* src = (const f32x4*)&O[(size_t)rows[i] * EXPR_D];
        v0[i] = src[lane];
        v1[i] = src[lane + 64];
    }
    #pragma unroll
    for (int i = 0; i < 4; ++i) {
        const int pos = base + i * 4 + wave;
        f32x4* dst = (f32x4*)&out[(size_t)pos * EXPR_D];
        __builtin_nontemporal_store(v0[i], &dst[lane]);
        __builtin_nontemporal_store(v1[i], &dst[lane + 64]);
    }
}

extern "C" void kernel_launch(void* const* d_in, const int* in_sizes, int n_in,
                              void* d_out, int out_size, void* d_ws, size_t ws_size,
                              hipStream_t stream) {
    const int*   token_type = (const int*)d_in[0];
    const int*   kos_idx    = (const int*)d_in[1];
    const int*   id_idx     = (const int*)d_in[2];
    const float* enc_ids    = (const float*)d_in[3];
    const float* kind_emb   = (const float*)d_in[4];
    const float* kos_emb    = (const float*)d_in[5];
    const float* Wp         = (const float*)d_in[6];
    const float* bp         = (const float*)d_in[7];
    const float* W2         = (const float*)d_in[8];
    const float* b2         = (const float*)d_in[9];
    float* out = (float*)d_out;

    char* ws = (char*)d_ws;
    int*   sel2   = (int*)ws;                          // 256 KiB
    float* kindc  = (float*)(ws + 262144);             // 16 KiB
    int2*  blkcnt = (int2*)(ws + 278528);              // 4 KiB
    u16*   Wt     = (u16*)(ws + 282624);               // 512 KiB
    u16*   Wt1    = (u16*)(ws + 806912);               // 256 KiB
    u16*   Thi    = (u16*)(ws + 1069056);              // TROWS*512*2 = 9306112
    float* O      = (float*)(ws + 10375168);           // TROWS*512*4 = 18612224 (~29 MB total)

    hipLaunchKernelGGL(prep_kernel, dim3(641), dim3(256), 0, stream,
                       W2, kind_emb, Wp, bp, token_type, Wt, Wt1, kindc, blkcnt);
    hipLaunchKernelGGL(scatter_kernel, dim3(256), dim3(256), 0, stream,
                       token_type, blkcnt, kos_idx, id_idx, sel2);
    hipLaunchKernelGGL(table_kernel, dim3(TROWS / 128, EXPR_D / 256), dim3(512), 0, stream,
                       enc_ids, kos_emb, Wt1, kindc, Thi);
    hipLaunchKernelGGL(table2_kernel, dim3(TROWS / 128, EXPR_D / 256), dim3(512), 0, stream,
                       Thi, Wt, b2, O);
    hipLaunchKernelGGL(gather_kernel, dim3(NPOS / 16), dim3(256), 0, stream,
                       sel2, O, out);
}